// Round 4
// baseline (1116.658 us; speedup 1.0000x reference)
//
#include <hip/hip_runtime.h>
#include <hip/hip_fp16.h>
#include <cstdint>
#include <cstddef>

typedef _Float16 half_t;
typedef _Float16 half8 __attribute__((ext_vector_type(8)));
typedef float f32x4 __attribute__((ext_vector_type(4)));

#define TAU_F 0.9f
#define S_ROWS 16384
#define DIN 384
#define DLAT 4096
#define DOUT 128
#define ZSTRIDE 8192   // halves: z row r lives in first 4096 halves of p-row slot r

// ---------------- K0a: f32 -> fp16 flat convert (x) ----------------
__launch_bounds__(256)
__global__ void k0_cvt(const float* __restrict__ in, half_t* __restrict__ out, int n) {
    int i = (blockIdx.x * 256 + threadIdx.x) * 8;
    if (i >= n) return;
    f32x4 a = *(const f32x4*)(in + i);
    f32x4 b = *(const f32x4*)(in + i + 4);
    half8 h;
    h[0] = (half_t)a[0]; h[1] = (half_t)a[1]; h[2] = (half_t)a[2]; h[3] = (half_t)a[3];
    h[4] = (half_t)b[0]; h[5] = (half_t)b[1]; h[6] = (half_t)b[2]; h[7] = (half_t)b[3];
    *(half8*)(out + i) = h;
}

// ------------- K0b: transpose + convert: in[R][C] f32 -> out[C][R] fp16 -------------
__launch_bounds__(256)
__global__ void k0_tcvt(const float* __restrict__ in, half_t* __restrict__ out, int R, int C) {
    __shared__ float tile[64][65];
    const int rb = blockIdx.x * 64, cb = blockIdx.y * 64;
    const int t = threadIdx.x;
    const int lc = t & 63, lr0 = t >> 6;   // 4 rows per pass
#pragma unroll
    for (int i = 0; i < 16; ++i) {
        int lr = lr0 + i * 4;
        tile[lr][lc] = in[(size_t)(rb + lr) * C + cb + lc];
    }
    __syncthreads();
#pragma unroll
    for (int i = 0; i < 16; ++i) {
        int oc = lr0 + i * 4;              // local col of input = row of output
        out[(size_t)(cb + oc) * R + rb + lc] = (half_t)tile[lc][oc];
    }
}

// ---------------- K1: z = x @ W_enc + b_enc  (fp16 MFMA, z -> strided fp16 in p-region) ----------------
// tile 128x128, BK=64, 4 waves (2x2), each wave 64x64 (4x4 frags of 16x16x32)
__launch_bounds__(256, 2)
__global__ void k1_gemm1(const half_t* __restrict__ x16,   // [S][384]
                         const half_t* __restrict__ weT,   // [4096][384]  (W_enc^T)
                         const float*  __restrict__ benc,  // [4096]
                         half_t* __restrict__ zbuf)        // [S][ZSTRIDE], data in first 4096
{
    const int bid = blockIdx.x;
    const int m0 = (bid >> 5) * 128;      // 16384/128 = 128 m-blocks
    const int n0 = (bid & 31) * 128;      // 4096/128  = 32 n-blocks
    const int t = threadIdx.x;
    const int w = t >> 6, lane = t & 63;
    const int wr = (w >> 1) * 64, wc = (w & 1) * 64;

    // padded stride 72 halves (144B) -> ~2-way (free) bank aliasing on frag reads
    __shared__ __align__(16) half_t smem[2 * 128 * 72];
    half_t* Asm = smem;
    half_t* Bsm = smem + 128 * 72;

    const int srow = t >> 3;              // 0..31
    const int scol = (t & 7) * 8;         // halves

    f32x4 acc[4][4] = {};

    for (int k0 = 0; k0 < DIN; k0 += 64) {
        __syncthreads();
#pragma unroll
        for (int p = 0; p < 4; ++p) {
            int r = srow + p * 32;
            half8 av = *(const half8*)(x16 + (size_t)(m0 + r) * DIN + k0 + scol);
            *(half8*)(Asm + r * 72 + scol) = av;
            half8 bv = *(const half8*)(weT + (size_t)(n0 + r) * DIN + k0 + scol);
            *(half8*)(Bsm + r * 72 + scol) = bv;
        }
        __syncthreads();
#pragma unroll
        for (int kk = 0; kk < 2; ++kk) {
            half8 af[4], bf[4];
#pragma unroll
            for (int i = 0; i < 4; ++i) {
                af[i] = *(const half8*)(Asm + (wr + i * 16 + (lane & 15)) * 72 + kk * 32 + (lane >> 4) * 8);
                bf[i] = *(const half8*)(Bsm + (wc + i * 16 + (lane & 15)) * 72 + kk * 32 + (lane >> 4) * 8);
            }
#pragma unroll
            for (int i = 0; i < 4; ++i)
#pragma unroll
                for (int j = 0; j < 4; ++j)
                    acc[i][j] = __builtin_amdgcn_mfma_f32_16x16x32_f16(af[i], bf[j], acc[i][j], 0, 0, 0);
        }
    }

    // epilogue: +b_enc, cvt fp16, LDS bounce for coalesced strided z stores
    __syncthreads();
    half_t* Osm = smem;                   // reuse as [128][128]
#pragma unroll
    for (int i = 0; i < 4; ++i)
#pragma unroll
        for (int j = 0; j < 4; ++j) {
            int col = wc + j * 16 + (lane & 15);
            float bd = benc[n0 + col];
#pragma unroll
            for (int r = 0; r < 4; ++r) {
                int row = wr + i * 16 + (lane >> 4) * 4 + r;
                Osm[row * 128 + col] = (half_t)(acc[i][j][r] + bd);
            }
        }
    __syncthreads();
    // store all 128x128 halves: 8 passes x 256 threads x half8;
    // 16 consecutive lanes cover one contiguous 256B row segment (coalesced)
#pragma unroll
    for (int q = 0; q < 8; ++q) {
        int idx = q * 256 + t;            // 0..2047
        int row = idx >> 4;               // 0..127
        int col = (idx & 15) * 8;         // 0..120
        half8 v = *(const half8*)(Osm + row * 128 + col);
        *(half8*)(zbuf + (size_t)(m0 + row) * ZSTRIDE + n0 + col) = v;
    }
}

// ---------------- K2: per-row softmax + adaptive-top-k threshold + p/latents outputs ----------------
// BARRIER-FREE: one wave per row (4 rows / 256-thread block). 64 elems/lane in regs.
// All cross-lane reductions via shfl; per-wave 256-bin histogram in LDS (same-wave ds
// ordering + threadfence_block only). 2 radix rounds -> bin width 2.75e-4; mask boundary
// sits at z ~ -0.41 (relu-dead), so bin-width jitter cannot change any output.
__launch_bounds__(256)
__global__ void k2_softsel(const half_t* __restrict__ zbuf,  // [S][ZSTRIDE]
                           float* __restrict__ p_out,        // [S][4096] (aliases zbuf slots)
                           float* __restrict__ lat_out)      // [S][4096]
{
    const int wid  = threadIdx.x >> 6;
    const int lane = threadIdx.x & 63;
    const int row  = (blockIdx.x << 2) + wid;
    __shared__ float hist[4][256];
    float* h = hist[wid];

    const half_t* zr = zbuf + (size_t)row * ZSTRIDE;
    float zf[64];
#pragma unroll
    for (int c = 0; c < 8; ++c) {
        half8 v = *(const half8*)(zr + c * 512 + lane * 8);
#pragma unroll
        for (int j = 0; j < 8; ++j) zf[c * 8 + j] = (float)v[j];
    }

    // row max (wave-local)
    float m = zf[0];
#pragma unroll
    for (int i = 1; i < 64; ++i) m = fmaxf(m, zf[i]);
#pragma unroll
    for (int off = 32; off > 0; off >>= 1) m = fmaxf(m, __shfl_xor(m, off));

    // zero hist (4 bins/lane)
    h[lane] = 0.f; h[lane + 64] = 0.f; h[lane + 128] = 0.f; h[lane + 192] = 0.f;
    __threadfence_block();

    const float lo1   = m - 18.0f;
    const float w1    = 18.0625f / 256.0f;
    const float invw1 = 256.0f / 18.0625f;

    // fused: exp-sum + round-1 histogram
    float ssum = 0.f;
#pragma unroll
    for (int i = 0; i < 64; ++i) {
        float e = __expf(zf[i] - m);
        ssum += e;
        int b = (int)((zf[i] - lo1) * invw1);   // trunc==floor for >=0; negatives clamp anyway
        b = b < 0 ? 0 : (b > 255 ? 255 : b);
        atomicAdd(&h[b], e);
    }
#pragma unroll
    for (int off = 32; off > 0; off >>= 1) ssum += __shfl_xor(ssum, off);
    const float T = TAU_F * ssum;
    __threadfence_block();

    // ---- 2 radix rounds: in-wave suffix-scan of 256 bins (lane owns bins 4l..4l+3)
    float lo = lo1, wdt = w1, A = 0.f;
#pragma unroll 1
    for (int rnd = 0; rnd < 2; ++rnd) {
        f32x4 hv = *(const f32x4*)(h + lane * 4);
        float s3 = hv[3];
        float s2 = hv[2] + s3;
        float s1 = hv[1] + s2;
        float s0 = hv[0] + s1;
        float tsum = s0;
        float S = tsum;                      // inclusive suffix scan over lane totals
#pragma unroll
        for (int off = 1; off < 64; off <<= 1) {
            float v = __shfl_down(S, off);
            if (lane + off < 64) S += v;
        }
        float excl = S - tsum;
        float f0 = s0 + excl, f1 = s1 + excl, f2 = s2 + excl, f3 = s3 + excl;
        const float need = T - A;
        int cand = -1;
        if (f0 >= need) cand = 0;
        if (f1 >= need) cand = 1;
        if (f2 >= need) cand = 2;
        if (f3 >= need) cand = 3;
        int binc = (cand >= 0) ? lane * 4 + cand : -1;
#pragma unroll
        for (int off = 32; off > 0; off >>= 1) binc = max(binc, __shfl_xor(binc, off));
        const int bs = binc;                 // >= 0 guaranteed (suffix at bin0 == ssum >= T)

        // A_next = A + suffix-above-bs = A + (f[bs&3] - hv[bs&3]) from owner lane bs>>2
        int q = bs & 3;
        float fq = (q == 0) ? f0 : (q == 1) ? f1 : (q == 2) ? f2 : f3;
        float hq = (q == 0) ? hv[0] : (q == 1) ? hv[1] : (q == 2) ? hv[2] : hv[3];
        float Anext = A + __shfl(fq - hq, bs >> 2);

        float lo_new = lo + bs * wdt;
        if (rnd == 0) {
            __threadfence_block();
            h[lane] = 0.f; h[lane + 64] = 0.f; h[lane + 128] = 0.f; h[lane + 192] = 0.f;
            __threadfence_block();
            const float invw2 = invw1 * 256.0f;
#pragma unroll
            for (int i = 0; i < 64; ++i) {
                int b = (int)((zf[i] - lo1) * invw1);
                b = b < 0 ? 0 : (b > 255 ? 255 : b);
                if (b == bs) {
                    int b2 = (int)((zf[i] - lo_new) * invw2);
                    b2 = b2 < 0 ? 0 : (b2 > 255 ? 255 : b2);
                    atomicAdd(&h[b2], __expf(zf[i] - m));
                }
            }
            __threadfence_block();
        }
        lo = lo_new;
        wdt *= (1.0f / 256.0f);
        A = Anext;
    }
    const float vthr = lo;                   // lower edge of final bin (width 2.75e-4)
    const float invS = 1.0f / ssum;

    // outputs: per-lane 8 chunks of 8 contiguous f32 (wave covers 2KB contiguous per chunk)
#pragma unroll
    for (int c = 0; c < 8; ++c) {
        f32x4 pv0, pv1, lv0, lv1;
#pragma unroll
        for (int j = 0; j < 4; ++j) {
            float z0 = zf[c * 8 + j], z1 = zf[c * 8 + 4 + j];
            pv0[j] = __expf(z0 - m) * invS;
            pv1[j] = __expf(z1 - m) * invS;
            lv0[j] = (z0 > 0.f && z0 >= vthr) ? z0 : 0.f;
            lv1[j] = (z1 > 0.f && z1 >= vthr) ? z1 : 0.f;
        }
        size_t base = (size_t)row * DLAT + c * 512 + lane * 8;
        *(f32x4*)(p_out + base) = pv0;       // overwrites this row's z slot (only we read it)
        *(f32x4*)(p_out + base + 4) = pv1;
        *(f32x4*)(lat_out + base) = lv0;
        *(f32x4*)(lat_out + base + 4) = lv1;
    }
}

// ---------------- K3: recon = tanh(latents @ W_dec + b_dec) ----------------
// tile 32x128 -> 512 blocks (2/CU); reg-staged prefetch hides HBM latency under MFMA.
// 4 waves, each wave 32x32 (2x2 frags of 16x16x32)
__launch_bounds__(256, 2)
__global__ void k3_gemm2(const float* __restrict__ lat,    // [S][4096]
                         const half_t* __restrict__ wdT,   // [128][4096] (W_dec^T)
                         const float* __restrict__ bdec,   // [128]
                         float* __restrict__ recon)        // [S][128]
{
    const int m0 = blockIdx.x * 32;
    const int t = threadIdx.x;
    const int w = t >> 6, lane = t & 63;
    const int wc = w * 32;

    __shared__ __align__(16) half_t Asm[32 * 72];
    __shared__ __align__(16) half_t Bsm[128 * 72];
    const int srow = t >> 3;            // 0..31
    const int scol = (t & 7) * 8;

    f32x4 acc[2][2] = {};
    f32x4 a0, a1;
    half8 breg[4];

    {   // prologue loads (k0 = 0)
        const float* src = lat + (size_t)(m0 + srow) * DLAT + scol;
        a0 = *(const f32x4*)src; a1 = *(const f32x4*)(src + 4);
#pragma unroll
        for (int p = 0; p < 4; ++p)
            breg[p] = *(const half8*)(wdT + (size_t)(srow + p * 32) * DLAT + scol);
    }

    for (int k0 = 0; k0 < DLAT; k0 += 64) {
        half8 hv;
#pragma unroll
        for (int i = 0; i < 4; ++i) { hv[i] = (half_t)a0[i]; hv[4 + i] = (half_t)a1[i]; }
        __syncthreads();                       // prior-iter LDS reads complete
        *(half8*)(Asm + srow * 72 + scol) = hv;
#pragma unroll
        for (int p = 0; p < 4; ++p)
            *(half8*)(Bsm + (srow + p * 32) * 72 + scol) = breg[p];
        __syncthreads();
        if (k0 + 64 < DLAT) {                  // prefetch next tile; latency hides under MFMA
            const float* src = lat + (size_t)(m0 + srow) * DLAT + k0 + 64 + scol;
            a0 = *(const f32x4*)src; a1 = *(const f32x4*)(src + 4);
#pragma unroll
            for (int p = 0; p < 4; ++p)
                breg[p] = *(const half8*)(wdT + (size_t)(srow + p * 32) * DLAT + k0 + 64 + scol);
        }
#pragma unroll
        for (int kk = 0; kk < 2; ++kk) {
            half8 af[2], bf[2];
#pragma unroll
            for (int i = 0; i < 2; ++i)
                af[i] = *(const half8*)(Asm + (i * 16 + (lane & 15)) * 72 + kk * 32 + (lane >> 4) * 8);
#pragma unroll
            for (int j = 0; j < 2; ++j)
                bf[j] = *(const half8*)(Bsm + (wc + j * 16 + (lane & 15)) * 72 + kk * 32 + (lane >> 4) * 8);
#pragma unroll
            for (int i = 0; i < 2; ++i)
#pragma unroll
                for (int j = 0; j < 2; ++j)
                    acc[i][j] = __builtin_amdgcn_mfma_f32_16x16x32_f16(af[i], bf[j], acc[i][j], 0, 0, 0);
        }
    }

#pragma unroll
    for (int i = 0; i < 2; ++i)
#pragma unroll
        for (int j = 0; j < 2; ++j) {
            int col = wc + j * 16 + (lane & 15);
            float bd = bdec[col];
#pragma unroll
            for (int r = 0; r < 4; ++r) {
                int row = m0 + i * 16 + (lane >> 4) * 4 + r;
                recon[(size_t)row * DOUT + col] = tanhf(acc[i][j][r] + bd);
            }
        }
}

// ---------------- launch ----------------
extern "C" void kernel_launch(void* const* d_in, const int* in_sizes, int n_in,
                              void* d_out, int out_size, void* d_ws, size_t ws_size,
                              hipStream_t stream) {
    (void)in_sizes; (void)n_in; (void)out_size; (void)ws_size;
    const float* x    = (const float*)d_in[0];
    const float* Wenc = (const float*)d_in[1];
    const float* benc = (const float*)d_in[2];
    const float* Wdec = (const float*)d_in[3];
    const float* bdec = (const float*)d_in[4];

    float* recon = (float*)d_out;                        // [16384][128]
    float* p_out = (float*)d_out + 2097152;              // [16384][4096]
    float* l_out = (float*)d_out + 69206016;             // [16384][4096]
    half_t* zbuf = (half_t*)p_out;                       // z16 interleaved in p slots

    char* ws = (char*)d_ws;                              // 16 MB total
    half_t* x16 = (half_t*)(ws);                         // 12,582,912 B
    half_t* weT = (half_t*)(ws + 12582912);              //  3,145,728 B
    half_t* wdT = (half_t*)(ws + 15728640);              //  1,048,576 B

    hipLaunchKernelGGL(k0_cvt,  dim3(3072),   dim3(256), 0, stream, x, x16, S_ROWS * DIN);
    hipLaunchKernelGGL(k0_tcvt, dim3(6, 64),  dim3(256), 0, stream, Wenc, weT, DIN, DLAT);
    hipLaunchKernelGGL(k0_tcvt, dim3(64, 2),  dim3(256), 0, stream, Wdec, wdT, DLAT, DOUT);
    hipLaunchKernelGGL(k1_gemm1, dim3(4096),  dim3(256), 0, stream, x16, weT, benc, zbuf);
    hipLaunchKernelGGL(k2_softsel, dim3(4096), dim3(256), 0, stream, zbuf, p_out, l_out);
    hipLaunchKernelGGL(k3_gemm2, dim3(512),   dim3(256), 0, stream, l_out, wdT, bdec, recon);
}